// Round 1
// baseline (1976.654 us; speedup 1.0000x reference)
//
#include <hip/hip_runtime.h>

// Self-attention (SAGAN-style), B=4, C=512, N=64*64=4096, O=64, fp32.
// out = gamma * (h @ softmax_axis1(f^T g)) + x
// Round 0: correct fp32 baseline. 3 kernels:
//   1) proj:  fgh[b,r,n] = W[r,:] @ x[b,:,n] + bias[r], r in [0,640)
//   2) stats: per query m: max_n / sumexp_n of logits l_n = <f[:,n], g[:,m]>
//   3) attn:  out[b,c,m] = gamma * sum_n h[b,c,n] * p[n,m] + x[b,c,m]
// Workspace: fgh 40 MB + rmax/rsum 128 KB.

#define N_PIX 4096
#define C_IN  512
#define R_ALL 640   // 64 f + 64 g + 512 h

// ---------------------------------------------------------------------------
// Kernel 1: projections. grid (N/128, 10, B), block 256.
// Each block: 64 rows x 128 cols output tile, K=512 in chunks of 32.
__global__ __launch_bounds__(256) void proj_kernel(
    const float* __restrict__ x,
    const float* __restrict__ f_w, const float* __restrict__ f_b,
    const float* __restrict__ g_w, const float* __restrict__ g_b,
    const float* __restrict__ h_w, const float* __restrict__ h_b,
    float* __restrict__ fgh)
{
    __shared__ __align__(16) float Ws[64 * 33];   // pad 33: row reads hit distinct banks
    __shared__ __align__(16) float Xs[32 * 128];
    const int t  = threadIdx.x;
    const int n0 = blockIdx.x * 128;
    const int rt = blockIdx.y;      // 0:f, 1:g, 2..9:h rows (rt-2)*64
    const int b  = blockIdx.z;

    const float* W; const float* bias; int rbase;
    if (rt == 0)      { W = f_w; bias = f_b; rbase = 0; }
    else if (rt == 1) { W = g_w; bias = g_b; rbase = 0; }
    else              { W = h_w; bias = h_b; rbase = (rt - 2) * 64; }

    const int tx = t & 31;          // n-group: n = n0 + tx*4 + i
    const int ty = t >> 5;          // o-group: o = ty*8 + oo
    const int o_sub = ty * 8;

    float acc[8][4];
    #pragma unroll
    for (int i = 0; i < 8; ++i)
        #pragma unroll
        for (int j = 0; j < 4; ++j) acc[i][j] = 0.f;

    for (int ct = 0; ct < 16; ++ct) {
        const int c0 = ct * 32;
        // stage W tile 64x32 (coalesced rows)
        #pragma unroll
        for (int k = 0; k < 8; ++k) {
            int e = t + k * 256;
            int o = e >> 5, c = e & 31;
            Ws[o * 33 + c] = W[(size_t)(rbase + o) * C_IN + c0 + c];
        }
        // stage x tile 32x128 (float4 coalesced)
        #pragma unroll
        for (int k = 0; k < 4; ++k) {
            int off = (t + k * 256) * 4;
            int cc = off >> 7, nn = off & 127;
            float4 xv = *(const float4*)&x[((size_t)(b * C_IN + c0 + cc)) * N_PIX + n0 + nn];
            *(float4*)&Xs[cc * 128 + nn] = xv;
        }
        __syncthreads();
        #pragma unroll 8
        for (int c = 0; c < 32; ++c) {
            float4 xv = *(const float4*)&Xs[c * 128 + tx * 4];
            #pragma unroll
            for (int oo = 0; oo < 8; ++oo) {
                float wv = Ws[(o_sub + oo) * 33 + c];
                acc[oo][0] += wv * xv.x;
                acc[oo][1] += wv * xv.y;
                acc[oo][2] += wv * xv.z;
                acc[oo][3] += wv * xv.w;
            }
        }
        __syncthreads();
    }
    #pragma unroll
    for (int oo = 0; oo < 8; ++oo) {
        int r = rt * 64 + o_sub + oo;
        float bv = bias[rbase + o_sub + oo];
        float4 o4 = make_float4(acc[oo][0] + bv, acc[oo][1] + bv,
                                acc[oo][2] + bv, acc[oo][3] + bv);
        *(float4*)&fgh[((size_t)(b * R_ALL + r)) * N_PIX + n0 + tx * 4] = o4;
    }
}

// ---------------------------------------------------------------------------
// Kernel 2: softmax stats per query column m. grid (N/32, B), block 256.
// Online (max, sumexp) over n in tiles of 32.
__global__ __launch_bounds__(256) void stats_kernel(
    const float* __restrict__ fgh,
    float* __restrict__ rmax_g, float* __restrict__ rsum_g)
{
    __shared__ __align__(16) float Gs[64 * 32];
    __shared__ __align__(16) float Fs[64 * 32];
    __shared__ float red[8 * 32];
    __shared__ float tmax_s[32];
    __shared__ float rmax_s[32];
    __shared__ float rsum_s[32];
    const int t  = threadIdx.x;
    const int m0 = blockIdx.x * 32;
    const int b  = blockIdx.y;
    const float* fbase = fgh + (size_t)(b * R_ALL) * N_PIX;
    const float* gbase = fbase + (size_t)64 * N_PIX;

    #pragma unroll
    for (int k = 0; k < 8; ++k) {
        int e = t + k * 256;
        int o = e >> 5, mm = e & 31;
        Gs[o * 32 + mm] = gbase[(size_t)o * N_PIX + m0 + mm];
    }
    if (t < 32) { rmax_s[t] = -1e30f; rsum_s[t] = 0.f; }
    __syncthreads();

    const int m  = t & 31;
    const int ng = t >> 5;   // 8 groups x 4 n
    for (int nt = 0; nt < 128; ++nt) {
        const int n0 = nt * 32;
        #pragma unroll
        for (int k = 0; k < 8; ++k) {
            int e = t + k * 256;
            int o = e >> 5, nn = e & 31;
            Fs[o * 32 + nn] = fbase[(size_t)o * N_PIX + n0 + nn];
        }
        __syncthreads();
        float s0 = 0, s1 = 0, s2 = 0, s3 = 0;
        #pragma unroll 16
        for (int o = 0; o < 64; ++o) {
            float gv = Gs[o * 32 + m];
            float4 f4 = *(const float4*)&Fs[o * 32 + ng * 4];
            s0 += f4.x * gv; s1 += f4.y * gv; s2 += f4.z * gv; s3 += f4.w * gv;
        }
        float ml = fmaxf(fmaxf(s0, s1), fmaxf(s2, s3));
        red[ng * 32 + m] = ml;
        __syncthreads();
        if (t < 32) {
            float v = red[t];
            #pragma unroll
            for (int g2 = 1; g2 < 8; ++g2) v = fmaxf(v, red[g2 * 32 + t]);
            tmax_s[t] = v;
        }
        __syncthreads();
        float tm = tmax_s[m];
        float partial = __expf(s0 - tm) + __expf(s1 - tm) +
                        __expf(s2 - tm) + __expf(s3 - tm);
        red[ng * 32 + m] = partial;
        __syncthreads();
        if (t < 32) {
            float v = 0.f;
            #pragma unroll
            for (int g2 = 0; g2 < 8; ++g2) v += red[g2 * 32 + t];
            float tmv = tmax_s[t];
            float rm = rmax_s[t], rs = rsum_s[t];
            if (tmv > rm) { rs = rs * __expf(rm - tmv) + v; rm = tmv; }
            else          { rs += v * __expf(tmv - rm); }
            rmax_s[t] = rm; rsum_s[t] = rs;
        }
        __syncthreads();
    }
    if (t < 32) {
        rmax_g[b * N_PIX + m0 + t] = rmax_s[t];
        rsum_g[b * N_PIX + m0 + t] = rsum_s[t];
    }
}

// ---------------------------------------------------------------------------
// Kernel 3: attention accumulate + epilogue. grid (N/64, B), block 512.
// Per block: 64 queries (m-tile), all 512 channels. acc 64 floats/thread.
__global__ __launch_bounds__(512) void attn_kernel(
    const float* __restrict__ fgh, const float* __restrict__ x,
    const float* __restrict__ rmax_g, const float* __restrict__ rsum_g,
    const float* __restrict__ gamma_p, float* __restrict__ out)
{
    __shared__ __align__(16) float Gs[64 * 64];    // 16 KB
    __shared__ __align__(16) float Fs[64 * 32];    //  8 KB
    __shared__ __align__(16) float Ps[32 * 64];    //  8 KB  [n][m]
    __shared__ __align__(16) float Hs[128 * 36];   // 18 KB  rows padded to 36 (16B-aligned, conflict-free)
    __shared__ float smax[64], sinv[64];
    const int t  = threadIdx.x;
    const int m0 = blockIdx.x * 64;
    const int b  = blockIdx.y;
    const float* fbase = fgh + (size_t)(b * R_ALL) * N_PIX;
    const float* gbase = fbase + (size_t)64  * N_PIX;
    const float* hbase = fbase + (size_t)128 * N_PIX;

    #pragma unroll
    for (int k = 0; k < 8; ++k) {
        int e = t + k * 512;
        int o = e >> 6, mm = e & 63;
        Gs[o * 64 + mm] = gbase[(size_t)o * N_PIX + m0 + mm];
    }
    if (t < 64) {
        smax[t] = rmax_g[b * N_PIX + m0 + t];
        sinv[t] = 1.0f / rsum_g[b * N_PIX + m0 + t];
    }

    float acc[4][4][4];  // [h-chunk j][k: c = j*128 + ty + 32k][mi]
    #pragma unroll
    for (int j = 0; j < 4; ++j)
        #pragma unroll
        for (int k = 0; k < 4; ++k)
            #pragma unroll
            for (int i = 0; i < 4; ++i) acc[j][k][i] = 0.f;

    const int m  = t & 63;   // S-phase mapping
    const int ng = t >> 6;   // 8 groups x 4 n
    const int mq = t & 15;   // attn-phase mapping: m = mq*4 + i
    const int ty = t >> 4;   // 0..31
    __syncthreads();

    for (int nt = 0; nt < 128; ++nt) {
        const int n0 = nt * 32;
        #pragma unroll
        for (int k = 0; k < 4; ++k) {
            int e = t + k * 512;
            int o = e >> 5, nn = e & 31;
            Fs[o * 32 + nn] = fbase[(size_t)o * N_PIX + n0 + nn];
        }
        __syncthreads();
        // S tile: 32 n x 64 m; this thread: 4 n for its m
        float s0 = 0, s1 = 0, s2 = 0, s3 = 0;
        #pragma unroll 16
        for (int o = 0; o < 64; ++o) {
            float gv = Gs[o * 64 + m];
            float4 f4 = *(const float4*)&Fs[o * 32 + ng * 4];  // wave-broadcast
            s0 += f4.x * gv; s1 += f4.y * gv; s2 += f4.z * gv; s3 += f4.w * gv;
        }
        const float sm = smax[m], si = sinv[m];
        Ps[(ng * 4 + 0) * 64 + m] = __expf(s0 - sm) * si;
        Ps[(ng * 4 + 1) * 64 + m] = __expf(s1 - sm) * si;
        Ps[(ng * 4 + 2) * 64 + m] = __expf(s2 - sm) * si;
        Ps[(ng * 4 + 3) * 64 + m] = __expf(s3 - sm) * si;
        __syncthreads();

        #pragma unroll
        for (int j = 0; j < 4; ++j) {
            // stage h chunk: rows j*128 .. j*128+127, cols n0..n0+31
            #pragma unroll
            for (int k = 0; k < 2; ++k) {
                int off = (t + k * 512) * 4;
                int cc = off >> 5, nn = off & 31;
                float4 hv = *(const float4*)&hbase[(size_t)(j * 128 + cc) * N_PIX + n0 + nn];
                *(float4*)&Hs[cc * 36 + nn] = hv;
            }
            __syncthreads();
            #pragma unroll 4
            for (int n = 0; n < 32; ++n) {
                float4 p4 = *(const float4*)&Ps[n * 64 + mq * 4];
                #pragma unroll
                for (int k = 0; k < 4; ++k) {
                    float hv = Hs[(ty + 32 * k) * 36 + n];
                    acc[j][k][0] += hv * p4.x;
                    acc[j][k][1] += hv * p4.y;
                    acc[j][k][2] += hv * p4.z;
                    acc[j][k][3] += hv * p4.w;
                }
            }
            __syncthreads();
        }
    }

    const float gamma = gamma_p[0];
    #pragma unroll
    for (int j = 0; j < 4; ++j)
        #pragma unroll
        for (int k = 0; k < 4; ++k) {
            int c = j * 128 + ty + 32 * k;
            size_t base = ((size_t)(b * C_IN + c)) * N_PIX + m0 + mq * 4;
            float4 xv = *(const float4*)&x[base];
            float4 o4 = make_float4(gamma * acc[j][k][0] + xv.x,
                                    gamma * acc[j][k][1] + xv.y,
                                    gamma * acc[j][k][2] + xv.z,
                                    gamma * acc[j][k][3] + xv.w);
            *(float4*)&out[base] = o4;
        }
}

// ---------------------------------------------------------------------------
extern "C" void kernel_launch(void* const* d_in, const int* in_sizes, int n_in,
                              void* d_out, int out_size, void* d_ws, size_t ws_size,
                              hipStream_t stream)
{
    const float* x     = (const float*)d_in[0];
    const float* f_w   = (const float*)d_in[1];
    const float* f_b   = (const float*)d_in[2];
    const float* g_w   = (const float*)d_in[3];
    const float* g_b   = (const float*)d_in[4];
    const float* h_w   = (const float*)d_in[5];
    const float* h_b   = (const float*)d_in[6];
    const float* gamma = (const float*)d_in[7];
    float* out = (float*)d_out;

    float* fgh    = (float*)d_ws;                       // 4*640*4096 floats = 40 MB
    float* rmax_g = fgh + (size_t)4 * R_ALL * N_PIX;    // 16384 floats
    float* rsum_g = rmax_g + 4 * N_PIX;                 // 16384 floats

    dim3 g1(N_PIX / 128, R_ALL / 64, 4);
    proj_kernel<<<g1, 256, 0, stream>>>(x, f_w, f_b, g_w, g_b, h_w, h_b, fgh);

    dim3 g2(N_PIX / 32, 4);
    stats_kernel<<<g2, 256, 0, stream>>>(fgh, rmax_g, rsum_g);

    dim3 g3(N_PIX / 64, 4);
    attn_kernel<<<g3, 512, 0, stream>>>(fgh, x, rmax_g, rsum_g, gamma, out);
}

// Round 2
// 418.907 us; speedup vs baseline: 4.7186x; 4.7186x over previous
//
#include <hip/hip_runtime.h>

// Self-attention (SAGAN-style), B=4, C=512, N=4096, O=64.
// Round 2: bf16 MFMA fused attention.
//   proj: fp32 LDS-tiled GEMM -> writes f/g/h as bf16 in MFMA fragment layouts
//   attn: per block 64 queries x 512 channels, n-loop of 128:
//         S = f^T g via mfma_32x32x16_bf16 (no max-subtract softmax),
//         E=exp(S) -> LDS (272B-padded rows), PV via mfma, fused denominator,
//         epilogue out = gamma * O/den + x.
// Fragment layouts (32-row tiles, k-octets selected by lane>>5):
//   A-layout elem (r,k): [tile=r>>5][q=k>>4][lane=(r&31)+32*((k>>3)&1)][i=k&7]
//   B-layout elem (k,c): [tile=c>>5][q=k>>4][lane=(c&31)+32*((k>>3)&1)][i=k&7]

#define N_PIX 4096
#define C_IN  512

typedef __attribute__((ext_vector_type(8)))  short bf16x8;
typedef __attribute__((ext_vector_type(16))) float f32x16;

__device__ inline unsigned int f2bf(float f) {
    union { float f; unsigned u; } x; x.f = f;
    unsigned r = x.u + 0x7FFFu + ((x.u >> 16) & 1u);
    return r >> 16;
}

// ---------------------------------------------------------------------------
// Kernel 1: projections. grid (N/128, 10, B), block 256.
__global__ __launch_bounds__(256) void proj_kernel(
    const float* __restrict__ x,
    const float* __restrict__ f_w, const float* __restrict__ f_b,
    const float* __restrict__ g_w, const float* __restrict__ g_b,
    const float* __restrict__ h_w, const float* __restrict__ h_b,
    unsigned short* __restrict__ fa, unsigned short* __restrict__ gbuf,
    unsigned short* __restrict__ ha)
{
    __shared__ __align__(16) float Ws[64 * 33];
    __shared__ __align__(16) float Xs[32 * 128];
    const int t  = threadIdx.x;
    const int n0 = blockIdx.x * 128;
    const int rt = blockIdx.y;      // 0:f, 1:g, 2..9:h rows (rt-2)*64
    const int b  = blockIdx.z;

    const float* W; const float* bias; int rbase;
    if (rt == 0)      { W = f_w; bias = f_b; rbase = 0; }
    else if (rt == 1) { W = g_w; bias = g_b; rbase = 0; }
    else              { W = h_w; bias = h_b; rbase = (rt - 2) * 64; }

    const int tx = t & 31;          // n = n0 + tx*4 + i
    const int ty = t >> 5;          // o = ty*8 + oo
    const int o_sub = ty * 8;

    float acc[8][4];
    #pragma unroll
    for (int i = 0; i < 8; ++i)
        #pragma unroll
        for (int j = 0; j < 4; ++j) acc[i][j] = 0.f;

    for (int ct = 0; ct < 16; ++ct) {
        const int c0 = ct * 32;
        #pragma unroll
        for (int k = 0; k < 8; ++k) {
            int e = t + k * 256;
            int o = e >> 5, c = e & 31;
            Ws[o * 33 + c] = W[(size_t)(rbase + o) * C_IN + c0 + c];
        }
        #pragma unroll
        for (int k = 0; k < 4; ++k) {
            int off = (t + k * 256) * 4;
            int cc = off >> 7, nn = off & 127;
            float4 xv = *(const float4*)&x[((size_t)(b * C_IN + c0 + cc)) * N_PIX + n0 + nn];
            *(float4*)&Xs[cc * 128 + nn] = xv;
        }
        __syncthreads();
        #pragma unroll 8
        for (int c = 0; c < 32; ++c) {
            float4 xv = *(const float4*)&Xs[c * 128 + tx * 4];
            #pragma unroll
            for (int oo = 0; oo < 8; ++oo) {
                float wv = Ws[(o_sub + oo) * 33 + c];
                acc[oo][0] += wv * xv.x;
                acc[oo][1] += wv * xv.y;
                acc[oo][2] += wv * xv.z;
                acc[oo][3] += wv * xv.w;
            }
        }
        __syncthreads();
    }

    if (rt < 2) {
        // f/g: 64xN, A-layout (f: rows=n? no, rows=n for S's A is f^T) --
        // both f and g use the "o is k" layout; f keyed by n (A), g keyed by m (B).
        unsigned short* dst = (rt == 0) ? fa : gbuf;
        float bvs[8];
        #pragma unroll
        for (int oo = 0; oo < 8; ++oo) bvs[oo] = bias[o_sub + oo];
        const int q  = o_sub >> 4;
        const int hf = (o_sub >> 3) & 1;
        #pragma unroll
        for (int i = 0; i < 4; ++i) {
            const int n = n0 + tx * 4 + i;
            uint4 pk;
            pk.x = f2bf(acc[0][i] + bvs[0]) | (f2bf(acc[1][i] + bvs[1]) << 16);
            pk.y = f2bf(acc[2][i] + bvs[2]) | (f2bf(acc[3][i] + bvs[3]) << 16);
            pk.z = f2bf(acc[4][i] + bvs[4]) | (f2bf(acc[5][i] + bvs[5]) << 16);
            pk.w = f2bf(acc[6][i] + bvs[6]) | (f2bf(acc[7][i] + bvs[7]) << 16);
            size_t off = (((size_t)(b * 128 + (n >> 5)) * 4 + q) * 512)
                       + (size_t)(((n & 31) + 32 * hf) * 8);
            *(uint4*)(dst + off) = pk;
        }
    } else {
        // h: 512xN, A-layout keyed by c (rows), k=n
        const int c0 = rbase + o_sub;
        const int ctile = c0 >> 5;
        const int n  = n0 + tx * 4;
        const int qg = n >> 4;
        const int hf = (n >> 3) & 1;
        const int ni = n & 7;   // 0 or 4
        #pragma unroll
        for (int oo = 0; oo < 8; ++oo) {
            const int c = c0 + oo;
            const float bv = bias[c];
            uint2 pk;
            pk.x = f2bf(acc[oo][0] + bv) | (f2bf(acc[oo][1] + bv) << 16);
            pk.y = f2bf(acc[oo][2] + bv) | (f2bf(acc[oo][3] + bv) << 16);
            size_t off = (((size_t)(b * 16 + ctile) * 256 + qg) * 512)
                       + (size_t)(((c & 31) + 32 * hf) * 8 + ni);
            *(uint2*)(ha + off) = pk;
        }
    }
}

// ---------------------------------------------------------------------------
// Kernel 2: fused attention. grid 256 (xcd-swizzled (b, m-block)), block 512.
__global__ __launch_bounds__(512) void attn_kernel(
    const unsigned short* __restrict__ fa,
    const unsigned short* __restrict__ gbuf,
    const unsigned short* __restrict__ ha,
    const float* __restrict__ x,
    const float* __restrict__ gamma_p,
    float* __restrict__ out)
{
    __shared__ unsigned short Ebuf[2][64 * 136];  // E[m][n], rows padded to 272B
    __shared__ float den_part[4][64];
    __shared__ float den_inv[64];

    const int t     = threadIdx.x;
    const int w     = t >> 6;        // wave 0..7
    const int l     = t & 63;
    const int lane  = l & 31;
    const int half  = l >> 5;
    const int nsub  = w & 3;         // S-phase n-subtile
    const int mhalf = w >> 2;        // S-phase m-half

    // XCD swizzle: batch b -> XCD pair, h (4MB) stays L2-resident
    const int blk = blockIdx.x;
    const int b   = (blk & 7) >> 1;
    const int mi  = ((blk >> 3) << 1) | (blk & 1);   // 0..63
    const int m0  = mi * 64;

    // persistent g fragments [mt][q]
    bf16x8 gfrag[2][4];
    {
        const unsigned short* gp = gbuf
            + (((size_t)(b * 128 + (m0 >> 5)) * 4) * 512) + (size_t)l * 8;
        #pragma unroll
        for (int mt = 0; mt < 2; ++mt)
            #pragma unroll
            for (int q = 0; q < 4; ++q)
                gfrag[mt][q] = *(const bf16x8*)(gp + ((size_t)mt * 4 + q) * 512);
    }

    f32x16 acc[2][2];
    #pragma unroll
    for (int i = 0; i < 2; ++i)
        #pragma unroll
        for (int j = 0; j < 2; ++j)
            #pragma unroll
            for (int r = 0; r < 16; ++r) acc[i][j][r] = 0.f;

    float denp = 0.f;

    const unsigned short* fbase = fa + ((size_t)b * 128 * 4) * 512;
    const unsigned short* hbase = ha + (((size_t)(b * 16 + w * 2)) * 256) * 512;

    for (int nt = 0; nt < 32; ++nt) {
        // ---- S phase: this wave's 32x32 tile (n-sub nsub, m-half mhalf) ----
        f32x16 s;
        #pragma unroll
        for (int r = 0; r < 16; ++r) s[r] = 0.f;
        const unsigned short* fp = fbase + ((size_t)(nt * 4 + nsub) * 4) * 512 + (size_t)l * 8;
        #pragma unroll
        for (int q = 0; q < 4; ++q) {
            bf16x8 af = *(const bf16x8*)(fp + (size_t)q * 512);
            s = __builtin_amdgcn_mfma_f32_32x32x16_bf16(af, gfrag[mhalf][q], s, 0, 0, 0);
        }
        // exp (no max-subtract: logits bounded ~12), denominator, pack to LDS
        unsigned short* ew = &Ebuf[nt & 1][(mhalf * 32 + lane) * 136 + nsub * 32 + half * 4];
        #pragma unroll
        for (int r4 = 0; r4 < 4; ++r4) {
            float e0 = __expf(s[r4 * 4 + 0]);
            float e1 = __expf(s[r4 * 4 + 1]);
            float e2 = __expf(s[r4 * 4 + 2]);
            float e3 = __expf(s[r4 * 4 + 3]);
            denp += (e0 + e1) + (e2 + e3);
            uint2 pk;
            pk.x = f2bf(e0) | (f2bf(e1) << 16);
            pk.y = f2bf(e2) | (f2bf(e3) << 16);
            *(uint2*)(ew + r4 * 8) = pk;   // rows n += 8 per r4 -> +8 shorts
        }
        __syncthreads();
        // ---- PV phase: acc[ct][mt] += h[c-tile] x E ----
        const unsigned short* hp = hbase + (size_t)(nt * 8) * 512 + (size_t)l * 8;
        const unsigned short* eb = &Ebuf[nt & 1][0];
        #pragma unroll
        for (int q = 0; q < 8; ++q) {
            bf16x8 a0 = *(const bf16x8*)(hp + (size_t)q * 512);
            bf16x8 a1 = *(const bf16x8*)(hp + (size_t)(256 * 512) + (size_t)q * 512);
            bf16x8 b0 = *(const bf16x8*)(eb + (lane)      * 136 + q * 16 + half * 8);
            bf16x8 b1 = *(const bf16x8*)(eb + (32 + lane) * 136 + q * 16 + half * 8);
            acc[0][0] = __builtin_amdgcn_mfma_f32_32x32x16_bf16(a0, b0, acc[0][0], 0, 0, 0);
            acc[0][1] = __builtin_amdgcn_mfma_f32_32x32x16_bf16(a0, b1, acc[0][1], 0, 0, 0);
            acc[1][0] = __builtin_amdgcn_mfma_f32_32x32x16_bf16(a1, b0, acc[1][0], 0, 0, 0);
            acc[1][1] = __builtin_amdgcn_mfma_f32_32x32x16_bf16(a1, b1, acc[1][1], 0, 0, 0);
        }
        // no second barrier: double-buffered E; next write targets other buffer
    }

    // ---- denominator reduction ----
    denp += __shfl_xor(denp, 32, 64);
    if (l < 32) den_part[nsub][mhalf * 32 + lane] = denp;
    __syncthreads();
    if (t < 64) {
        float d = den_part[0][t] + den_part[1][t] + den_part[2][t] + den_part[3][t];
        den_inv[t] = 1.0f / d;
    }
    __syncthreads();

    // ---- epilogue: out = gamma * O/den + x ----
    const float gs = gamma_p[0];
    #pragma unroll
    for (int ct = 0; ct < 2; ++ct) {
        #pragma unroll
        for (int mt = 0; mt < 2; ++mt) {
            const float dinv = den_inv[mt * 32 + lane];
            const int m = m0 + mt * 32 + lane;
            #pragma unroll
            for (int r = 0; r < 16; ++r) {
                const int c = w * 64 + ct * 32 + (r & 3) + ((r >> 2) * 8) + half * 4;
                const size_t idx = ((size_t)(b * C_IN + c)) * N_PIX + m;
                out[idx] = gs * acc[ct][mt][r] * dinv + x[idx];
            }
        }
    }
}

// ---------------------------------------------------------------------------
extern "C" void kernel_launch(void* const* d_in, const int* in_sizes, int n_in,
                              void* d_out, int out_size, void* d_ws, size_t ws_size,
                              hipStream_t stream)
{
    const float* x     = (const float*)d_in[0];
    const float* f_w   = (const float*)d_in[1];
    const float* f_b   = (const float*)d_in[2];
    const float* g_w   = (const float*)d_in[3];
    const float* g_b   = (const float*)d_in[4];
    const float* h_w   = (const float*)d_in[5];
    const float* h_b   = (const float*)d_in[6];
    const float* gamma = (const float*)d_in[7];
    float* out = (float*)d_out;

    unsigned short* fa   = (unsigned short*)d_ws;        // 2 MB (1M shorts)
    unsigned short* gbuf = fa + (1u << 20);              // 2 MB
    unsigned short* ha   = gbuf + (1u << 20);            // 16 MB

    dim3 g1(N_PIX / 128, 10, 4);
    proj_kernel<<<g1, 256, 0, stream>>>(x, f_w, f_b, g_w, g_b, h_w, h_b, fa, gbuf, ha);

    attn_kernel<<<256, 512, 0, stream>>>(fa, gbuf, ha, x, gamma, out);
}

// Round 3
// 297.968 us; speedup vs baseline: 6.6338x; 1.4059x over previous
//
#include <hip/hip_runtime.h>

// Self-attention (SAGAN-style), B=4, C=512, N=4096, O=64.
// Round 3: proj moved to bf16 MFMA (attn kernel unchanged from round 2).
//   pack_w:    f_w/g_w -> A-frag bf16; h_w -> B-frag bf16 (octets along c).
//   pack_x:    x fp32 -> bf16 frag layout keyed by n, octets along c
//              (serves as B-frag for f/g GEMM and A-frag for transposed h GEMM).
//   proj_gemm: y=0: [f;g] = W_fg @ x  (128x4096, K=512)
//              y=1..4: h^T slice = x^T @ h_w^T (4096x128, K=512)
//              epilogues write fa/gbuf/ha fragment buffers directly (uint2).
//   attn:      fused flash attention, same as round 2.
// Fragment chunk convention (32-row tiles):
//   chunk[tile][q][lane][i] = M[idx = tile*32 + (lane&31)][k = q*16 + (lane>>5)*8 + i]
//   (same math for A rows and B cols.)

#define N_PIX 4096
#define C_IN  512

typedef __attribute__((ext_vector_type(8)))  short bf16x8;
typedef __attribute__((ext_vector_type(16))) float f32x16;

__device__ inline unsigned int f2bf(float f) {
    union { float f; unsigned u; } x; x.f = f;
    unsigned r = x.u + 0x7FFFu + ((x.u >> 16) & 1u);
    return r >> 16;
}

// ---------------------------------------------------------------------------
// pack_w: 40960 octets total. [0,8192): wfg (f/g A-frag, 4 tiles);
// [8192,40960): whb (h B-frag, 16 tiles). grid 160, block 256.
__global__ __launch_bounds__(256) void pack_w(
    const float* __restrict__ f_w, const float* __restrict__ g_w,
    const float* __restrict__ h_w,
    unsigned short* __restrict__ wfg, unsigned short* __restrict__ whb)
{
    const int idx = blockIdx.x * 256 + threadIdx.x;
    const float* W;
    unsigned short* dst;
    int sub;
    if (idx < 8192) {
        const int ot = idx >> 11, rem = idx & 2047;
        const int q = rem >> 6, l = rem & 63;
        const int o = ot * 32 + (l & 31);
        W = (o < 64) ? &f_w[(size_t)o * C_IN] : &g_w[(size_t)(o - 64) * C_IN];
        dst = wfg; sub = idx;
        W += q * 16 + (l >> 5) * 8;
    } else {
        const int id2 = idx - 8192;
        const int ct = id2 >> 11, rem = id2 & 2047;
        const int q = rem >> 6, l = rem & 63;
        const int co = ct * 32 + (l & 31);
        W = &h_w[(size_t)co * C_IN + q * 16 + (l >> 5) * 8];
        dst = whb; sub = id2;
    }
    float4 v0 = *(const float4*)(W);
    float4 v1 = *(const float4*)(W + 4);
    uint4 pk;
    pk.x = f2bf(v0.x) | (f2bf(v0.y) << 16);
    pk.y = f2bf(v0.z) | (f2bf(v0.w) << 16);
    pk.z = f2bf(v1.x) | (f2bf(v1.y) << 16);
    pk.w = f2bf(v1.z) | (f2bf(v1.w) << 16);
    *(uint4*)&dst[(size_t)sub * 8] = pk;
}

// ---------------------------------------------------------------------------
// pack_x: x[b,c,n] fp32 -> xb frag chunks: content[i] = x[c=q*16+hf*8+i][n],
// addr ((b*128 + n>>5)*32 + q)*512 + ((n&31)+32*hf)*8.
// grid (64 n-tiles-of-64, 4 c-tiles-of-128, B), block 256.
__global__ __launch_bounds__(256) void pack_x(
    const float* __restrict__ x, unsigned short* __restrict__ xb)
{
    __shared__ unsigned short Ls[128 * 66];   // [c_local][n_local], row 66 shorts (33 words, odd)
    const int t  = threadIdx.x;
    const int n0 = blockIdx.x * 64;
    const int c0 = blockIdx.y * 128;
    const int b  = blockIdx.z;

    {
        const int c = t >> 1, half = t & 1;
        const float* xp = &x[((size_t)(b * C_IN + c0 + c)) * N_PIX + n0 + half * 32];
        #pragma unroll
        for (int k = 0; k < 8; ++k) {
            float4 v = *(const float4*)&xp[k * 4];
            uint2 pk;
            pk.x = f2bf(v.x) | (f2bf(v.y) << 16);
            pk.y = f2bf(v.z) | (f2bf(v.w) << 16);
            *(uint2*)&Ls[c * 66 + half * 32 + k * 4] = pk;
        }
    }
    __syncthreads();
    const int n = t & 63;
    #pragma unroll
    for (int p = 0; p < 4; ++p) {
        const int j = (t >> 6) + p * 4;   // 0..15 c-octet
        unsigned short tmp[8];
        #pragma unroll
        for (int k = 0; k < 8; ++k) tmp[k] = Ls[(j * 8 + k) * 66 + n];
        uint4 pk;
        pk.x = tmp[0] | ((unsigned)tmp[1] << 16);
        pk.y = tmp[2] | ((unsigned)tmp[3] << 16);
        pk.z = tmp[4] | ((unsigned)tmp[5] << 16);
        pk.w = tmp[6] | ((unsigned)tmp[7] << 16);
        const int cbase = c0 + j * 8;
        const int q  = cbase >> 4;
        const int hf = (cbase >> 3) & 1;
        const int ng = n0 + n;
        size_t off = (((size_t)(b * 128 + (ng >> 5)) * 32 + q) * 64
                      + ((ng & 31) + 32 * hf)) * 8;
        *(uint4*)&xb[off] = pk;
    }
}

// ---------------------------------------------------------------------------
// proj_gemm: grid (32, 5, B), block 256 (4 waves). 128x128 tile, K=512.
__global__ __launch_bounds__(256) void proj_gemm(
    const unsigned short* __restrict__ xb,
    const unsigned short* __restrict__ wfg,
    const unsigned short* __restrict__ whb,
    const float* __restrict__ f_b, const float* __restrict__ g_b,
    const float* __restrict__ h_b,
    unsigned short* __restrict__ fa, unsigned short* __restrict__ gbuf,
    unsigned short* __restrict__ ha)
{
    const int t = threadIdx.x;
    const int w = t >> 6;
    const int l = t & 63;
    const int bx = blockIdx.x, y = blockIdx.y, b = blockIdx.z;

    const unsigned short* aptr;
    const unsigned short* bptr;
    if (y == 0) {
        aptr = wfg + (size_t)(w * 32) * 512;
        bptr = xb  + (size_t)((b * 128 + bx * 4) * 32) * 512;
    } else {
        aptr = xb  + (size_t)((b * 128 + bx * 4 + w) * 32) * 512;
        bptr = whb + (size_t)(((y - 1) * 4) * 32) * 512;
    }
    aptr += (size_t)l * 8;
    bptr += (size_t)l * 8;

    f32x16 acc[4];
    #pragma unroll
    for (int ct = 0; ct < 4; ++ct)
        #pragma unroll
        for (int r = 0; r < 16; ++r) acc[ct][r] = 0.f;

    #pragma unroll 4
    for (int q = 0; q < 32; ++q) {
        bf16x8 av = *(const bf16x8*)(aptr + (size_t)q * 512);
        #pragma unroll
        for (int ct = 0; ct < 4; ++ct) {
            bf16x8 bv = *(const bf16x8*)(bptr + (size_t)(ct * 32 + q) * 512);
            acc[ct] = __builtin_amdgcn_mfma_f32_32x32x16_bf16(av, bv, acc[ct], 0, 0, 0);
        }
    }

    const int h = l >> 5;   // half
    if (y == 0) {
        // rows o = w*32 + pattern; cols n. f: w 0..1, g: w 2..3.
        unsigned short* buf = (w < 2) ? fa : gbuf;
        const float* bias = (w < 2) ? f_b : g_b;
        #pragma unroll
        for (int ct = 0; ct < 4; ++ct) {
            const int ntile = bx * 4 + ct;
            #pragma unroll
            for (int j = 0; j < 4; ++j) {
                const int o_base = (w & 1) * 32 + 8 * j + 4 * h;  // o within f or g
                float4 bv = *(const float4*)&bias[o_base];
                const int q  = o_base >> 4;
                const int i0 = 4 * h;
                const int lp = (l & 31) + 32 * (j & 1);
                uint2 pk;
                pk.x = f2bf(acc[ct][4 * j + 0] + bv.x) | (f2bf(acc[ct][4 * j + 1] + bv.y) << 16);
                pk.y = f2bf(acc[ct][4 * j + 2] + bv.z) | (f2bf(acc[ct][4 * j + 3] + bv.w) << 16);
                size_t off = (((size_t)(b * 128 + ntile) * 4 + q) * 64 + lp) * 8 + i0;
                *(uint2*)&buf[off] = pk;
            }
        }
    } else {
        // rows n = ntile*32 + pattern; cols c_out.
        const int ntile = bx * 4 + w;
        #pragma unroll
        for (int ct = 0; ct < 4; ++ct) {
            const int ctile = (y - 1) * 4 + ct;
            const float hb = h_b[ctile * 32 + (l & 31)];
            #pragma unroll
            for (int j = 0; j < 4; ++j) {
                const int q  = ntile * 2 + (j >> 1);
                const int i0 = 4 * h;
                const int lp = (l & 31) + 32 * (j & 1);
                uint2 pk;
                pk.x = f2bf(acc[ct][4 * j + 0] + hb) | (f2bf(acc[ct][4 * j + 1] + hb) << 16);
                pk.y = f2bf(acc[ct][4 * j + 2] + hb) | (f2bf(acc[ct][4 * j + 3] + hb) << 16);
                size_t off = (((size_t)(b * 16 + ctile) * 256 + q) * 64 + lp) * 8 + i0;
                *(uint2*)&ha[off] = pk;
            }
        }
    }
}

// ---------------------------------------------------------------------------
// attn: unchanged from round 2. grid 256, block 512.
__global__ __launch_bounds__(512) void attn_kernel(
    const unsigned short* __restrict__ fa,
    const unsigned short* __restrict__ gbuf,
    const unsigned short* __restrict__ ha,
    const float* __restrict__ x,
    const float* __restrict__ gamma_p,
    float* __restrict__ out)
{
    __shared__ unsigned short Ebuf[2][64 * 136];
    __shared__ float den_part[4][64];
    __shared__ float den_inv[64];

    const int t     = threadIdx.x;
    const int w     = t >> 6;
    const int l     = t & 63;
    const int lane  = l & 31;
    const int half  = l >> 5;
    const int nsub  = w & 3;
    const int mhalf = w >> 2;

    const int blk = blockIdx.x;
    const int b   = (blk & 7) >> 1;
    const int mi  = ((blk >> 3) << 1) | (blk & 1);
    const int m0  = mi * 64;

    bf16x8 gfrag[2][4];
    {
        const unsigned short* gp = gbuf
            + (((size_t)(b * 128 + (m0 >> 5)) * 4) * 512) + (size_t)l * 8;
        #pragma unroll
        for (int mt = 0; mt < 2; ++mt)
            #pragma unroll
            for (int q = 0; q < 4; ++q)
                gfrag[mt][q] = *(const bf16x8*)(gp + ((size_t)mt * 4 + q) * 512);
    }

    f32x16 acc[2][2];
    #pragma unroll
    for (int i = 0; i < 2; ++i)
        #pragma unroll
        for (int j = 0; j < 2; ++j)
            #pragma unroll
            for (int r = 0; r < 16; ++r) acc[i][j][r] = 0.f;

    float denp = 0.f;

    const unsigned short* fbase = fa + ((size_t)b * 128 * 4) * 512;
    const unsigned short* hbase = ha + (((size_t)(b * 16 + w * 2)) * 256) * 512;

    for (int nt = 0; nt < 32; ++nt) {
        f32x16 s;
        #pragma unroll
        for (int r = 0; r < 16; ++r) s[r] = 0.f;
        const unsigned short* fp = fbase + ((size_t)(nt * 4 + nsub) * 4) * 512 + (size_t)l * 8;
        #pragma unroll
        for (int q = 0; q < 4; ++q) {
            bf16x8 af = *(const bf16x8*)(fp + (size_t)q * 512);
            s = __builtin_amdgcn_mfma_f32_32x32x16_bf16(af, gfrag[mhalf][q], s, 0, 0, 0);
        }
        unsigned short* ew = &Ebuf[nt & 1][(mhalf * 32 + lane) * 136 + nsub * 32 + half * 4];
        #pragma unroll
        for (int r4 = 0; r4 < 4; ++r4) {
            float e0 = __expf(s[r4 * 4 + 0]);
            float e1 = __expf(s[r4 * 4 + 1]);
            float e2 = __expf(s[r4 * 4 + 2]);
            float e3 = __expf(s[r4 * 4 + 3]);
            denp += (e0 + e1) + (e2 + e3);
            uint2 pk;
            pk.x = f2bf(e0) | (f2bf(e1) << 16);
            pk.y = f2bf(e2) | (f2bf(e3) << 16);
            *(uint2*)(ew + r4 * 8) = pk;
        }
        __syncthreads();
        const unsigned short* hp = hbase + (size_t)(nt * 8) * 512 + (size_t)l * 8;
        const unsigned short* eb = &Ebuf[nt & 1][0];
        #pragma unroll
        for (int q = 0; q < 8; ++q) {
            bf16x8 a0 = *(const bf16x8*)(hp + (size_t)q * 512);
            bf16x8 a1 = *(const bf16x8*)(hp + (size_t)(256 * 512) + (size_t)q * 512);
            bf16x8 b0 = *(const bf16x8*)(eb + (lane)      * 136 + q * 16 + half * 8);
            bf16x8 b1 = *(const bf16x8*)(eb + (32 + lane) * 136 + q * 16 + half * 8);
            acc[0][0] = __builtin_amdgcn_mfma_f32_32x32x16_bf16(a0, b0, acc[0][0], 0, 0, 0);
            acc[0][1] = __builtin_amdgcn_mfma_f32_32x32x16_bf16(a0, b1, acc[0][1], 0, 0, 0);
            acc[1][0] = __builtin_amdgcn_mfma_f32_32x32x16_bf16(a1, b0, acc[1][0], 0, 0, 0);
            acc[1][1] = __builtin_amdgcn_mfma_f32_32x32x16_bf16(a1, b1, acc[1][1], 0, 0, 0);
        }
    }

    denp += __shfl_xor(denp, 32, 64);
    if (l < 32) den_part[nsub][mhalf * 32 + lane] = denp;
    __syncthreads();
    if (t < 64) {
        float d = den_part[0][t] + den_part[1][t] + den_part[2][t] + den_part[3][t];
        den_inv[t] = 1.0f / d;
    }
    __syncthreads();

    const float gs = gamma_p[0];
    #pragma unroll
    for (int ct = 0; ct < 2; ++ct) {
        #pragma unroll
        for (int mt = 0; mt < 2; ++mt) {
            const float dinv = den_inv[mt * 32 + lane];
            const int m = m0 + mt * 32 + lane;
            #pragma unroll
            for (int r = 0; r < 16; ++r) {
                const int c = w * 64 + ct * 32 + (r & 3) + ((r >> 2) * 8) + half * 4;
                const size_t idx = ((size_t)(b * C_IN + c)) * N_PIX + m;
                out[idx] = gs * acc[ct][mt][r] * dinv + x[idx];
            }
        }
    }
}

// ---------------------------------------------------------------------------
extern "C" void kernel_launch(void* const* d_in, const int* in_sizes, int n_in,
                              void* d_out, int out_size, void* d_ws, size_t ws_size,
                              hipStream_t stream)
{
    const float* x     = (const float*)d_in[0];
    const float* f_w   = (const float*)d_in[1];
    const float* f_b   = (const float*)d_in[2];
    const float* g_w   = (const float*)d_in[3];
    const float* g_b   = (const float*)d_in[4];
    const float* h_w   = (const float*)d_in[5];
    const float* h_b   = (const float*)d_in[6];
    const float* gamma = (const float*)d_in[7];
    float* out = (float*)d_out;

    unsigned short* fa   = (unsigned short*)d_ws;        // 1M shorts (2 MB)
    unsigned short* gbuf = fa + (1u << 20);              // 1M shorts
    unsigned short* ha   = gbuf + (1u << 20);            // 8M shorts (16 MB)
    unsigned short* xb   = ha + (8u << 20);              // 8M shorts (16 MB)
    unsigned short* wfg  = xb + (8u << 20);              // 64K shorts
    unsigned short* whb  = wfg + (1u << 16);             // 256K shorts

    pack_w<<<160, 256, 0, stream>>>(f_w, g_w, h_w, wfg, whb);

    dim3 gx(64, 4, 4);
    pack_x<<<gx, 256, 0, stream>>>(x, xb);

    dim3 gp(32, 5, 4);
    proj_gemm<<<gp, 256, 0, stream>>>(xb, wfg, whb, f_b, g_b, h_b, fa, gbuf, ha);

    attn_kernel<<<256, 512, 0, stream>>>(fa, gbuf, ha, x, gamma, out);
}

// Round 4
// 249.144 us; speedup vs baseline: 7.9338x; 1.1960x over previous
//
#include <hip/hip_runtime.h>

// Self-attention (SAGAN-style), B=4, C=512, N=4096, O=64.
// Round 4:
//   attn: 512 blocks (2/CU, 16 waves/CU): each block 64 queries x 256 channels,
//         S-phase duplicated across the channel-half pair (+11% FLOPs) to double
//         occupancy; __launch_bounds__(512,4) caps VGPR at 128.
//   proj_gemm: m97-style LDS staging via global_load_lds(16B). Frag buffers are
//         contiguous 1KB chunks -> wave-uniform-base DMA; B-frags reused by all
//         4 waves through conflict-free ds_read_b128.
//   pack_w / pack_x: unchanged.
// Fragment chunk convention (32-row tiles):
//   chunk[tile][q][lane][i] = M[idx = tile*32 + (lane&31)][k = q*16 + (lane>>5)*8 + i]

#define N_PIX 4096
#define C_IN  512

typedef __attribute__((ext_vector_type(8)))  short bf16x8;
typedef __attribute__((ext_vector_type(16))) float f32x16;

typedef __attribute__((address_space(1))) const unsigned int guint;
typedef __attribute__((address_space(3))) unsigned int luint;

__device__ __forceinline__ void gload_lds16(const void* g, void* l) {
    __builtin_amdgcn_global_load_lds((guint*)g, (luint*)l, 16, 0, 0);
}

__device__ inline unsigned int f2bf(float f) {
    union { float f; unsigned u; } x; x.f = f;
    unsigned r = x.u + 0x7FFFu + ((x.u >> 16) & 1u);
    return r >> 16;
}

// ---------------------------------------------------------------------------
// pack_w: 40960 octets. [0,8192): wfg (f/g A-frag); [8192,40960): whb (h B-frag).
__global__ __launch_bounds__(256) void pack_w(
    const float* __restrict__ f_w, const float* __restrict__ g_w,
    const float* __restrict__ h_w,
    unsigned short* __restrict__ wfg, unsigned short* __restrict__ whb)
{
    const int idx = blockIdx.x * 256 + threadIdx.x;
    const float* W;
    unsigned short* dst;
    int sub;
    if (idx < 8192) {
        const int ot = idx >> 11, rem = idx & 2047;
        const int q = rem >> 6, l = rem & 63;
        const int o = ot * 32 + (l & 31);
        W = (o < 64) ? &f_w[(size_t)o * C_IN] : &g_w[(size_t)(o - 64) * C_IN];
        dst = wfg; sub = idx;
        W += q * 16 + (l >> 5) * 8;
    } else {
        const int id2 = idx - 8192;
        const int ct = id2 >> 11, rem = id2 & 2047;
        const int q = rem >> 6, l = rem & 63;
        const int co = ct * 32 + (l & 31);
        W = &h_w[(size_t)co * C_IN + q * 16 + (l >> 5) * 8];
        dst = whb; sub = id2;
    }
    float4 v0 = *(const float4*)(W);
    float4 v1 = *(const float4*)(W + 4);
    uint4 pk;
    pk.x = f2bf(v0.x) | (f2bf(v0.y) << 16);
    pk.y = f2bf(v0.z) | (f2bf(v0.w) << 16);
    pk.z = f2bf(v1.x) | (f2bf(v1.y) << 16);
    pk.w = f2bf(v1.z) | (f2bf(v1.w) << 16);
    *(uint4*)&dst[(size_t)sub * 8] = pk;
}

// ---------------------------------------------------------------------------
// pack_x: x[b,c,n] fp32 -> frag chunks. grid (64, 4, B), block 256.
__global__ __launch_bounds__(256) void pack_x(
    const float* __restrict__ x, unsigned short* __restrict__ xb)
{
    __shared__ unsigned short Ls[128 * 66];
    const int t  = threadIdx.x;
    const int n0 = blockIdx.x * 64;
    const int c0 = blockIdx.y * 128;
    const int b  = blockIdx.z;

    {
        const int c = t >> 1, half = t & 1;
        const float* xp = &x[((size_t)(b * C_IN + c0 + c)) * N_PIX + n0 + half * 32];
        #pragma unroll
        for (int k = 0; k < 8; ++k) {
            float4 v = *(const float4*)&xp[k * 4];
            uint2 pk;
            pk.x = f2bf(v.x) | (f2bf(v.y) << 16);
            pk.y = f2bf(v.z) | (f2bf(v.w) << 16);
            *(uint2*)&Ls[c * 66 + half * 32 + k * 4] = pk;
        }
    }
    __syncthreads();
    const int n = t & 63;
    #pragma unroll
    for (int p = 0; p < 4; ++p) {
        const int j = (t >> 6) + p * 4;
        unsigned short tmp[8];
        #pragma unroll
        for (int k = 0; k < 8; ++k) tmp[k] = Ls[(j * 8 + k) * 66 + n];
        uint4 pk;
        pk.x = tmp[0] | ((unsigned)tmp[1] << 16);
        pk.y = tmp[2] | ((unsigned)tmp[3] << 16);
        pk.z = tmp[4] | ((unsigned)tmp[5] << 16);
        pk.w = tmp[6] | ((unsigned)tmp[7] << 16);
        const int cbase = c0 + j * 8;
        const int q  = cbase >> 4;
        const int hf = (cbase >> 3) & 1;
        const int ng = n0 + n;
        size_t off = (((size_t)(b * 128 + (ng >> 5)) * 32 + q) * 64
                      + ((ng & 31) + 32 * hf)) * 8;
        *(uint4*)&xb[off] = pk;
    }
}

// ---------------------------------------------------------------------------
// proj_gemm: grid (32, 5, B), block 256 (4 waves). 128x128 tile, K=512,
// LDS-staged in BK=64 steps via global_load_lds.
__global__ __launch_bounds__(256) void proj_gemm(
    const unsigned short* __restrict__ xb,
    const unsigned short* __restrict__ wfg,
    const unsigned short* __restrict__ whb,
    const float* __restrict__ f_b, const float* __restrict__ g_b,
    const float* __restrict__ h_b,
    unsigned short* __restrict__ fa, unsigned short* __restrict__ gbuf,
    unsigned short* __restrict__ ha)
{
    __shared__ __align__(16) unsigned short Ls[32 * 512];   // 32 KB: chunks 0-15 A, 16-31 B
    const int t = threadIdx.x;
    const int w = t >> 6;
    const int l = t & 63;
    const int bx = blockIdx.x, y = blockIdx.y, b = blockIdx.z;

    const unsigned short* abase;
    const unsigned short* bbase;
    if (y == 0) {
        abase = wfg;
        bbase = xb + (size_t)((b * 128 + bx * 4) * 32) * 512;
    } else {
        abase = xb + (size_t)((b * 128 + bx * 4) * 32) * 512;
        bbase = whb + (size_t)(((y - 1) * 4) * 32) * 512;
    }

    f32x16 acc[4];
    #pragma unroll
    for (int ct = 0; ct < 4; ++ct)
        #pragma unroll
        for (int r = 0; r < 16; ++r) acc[ct][r] = 0.f;

    for (int it = 0; it < 8; ++it) {
        #pragma unroll
        for (int j = 0; j < 8; ++j) {
            const int chunk = w * 8 + j;            // wave-uniform
            const unsigned short* src;
            if (chunk < 16)
                src = abase + (size_t)((chunk >> 2) * 32 + it * 4 + (chunk & 3)) * 512;
            else {
                const int c2 = chunk - 16;
                src = bbase + (size_t)((c2 >> 2) * 32 + it * 4 + (c2 & 3)) * 512;
            }
            gload_lds16(src + (size_t)l * 8, &Ls[chunk * 512]);
        }
        __syncthreads();
        #pragma unroll
        for (int qq = 0; qq < 4; ++qq) {
            bf16x8 av = *(const bf16x8*)&Ls[(w * 4 + qq) * 512 + l * 8];
            #pragma unroll
            for (int ct = 0; ct < 4; ++ct) {
                bf16x8 bv = *(const bf16x8*)&Ls[(16 + ct * 4 + qq) * 512 + l * 8];
                acc[ct] = __builtin_amdgcn_mfma_f32_32x32x16_bf16(av, bv, acc[ct], 0, 0, 0);
            }
        }
        __syncthreads();
    }

    const int h = l >> 5;
    if (y == 0) {
        unsigned short* buf = (w < 2) ? fa : gbuf;
        const float* bias = (w < 2) ? f_b : g_b;
        #pragma unroll
        for (int ct = 0; ct < 4; ++ct) {
            const int ntile = bx * 4 + ct;
            #pragma unroll
            for (int j = 0; j < 4; ++j) {
                const int o_base = (w & 1) * 32 + 8 * j + 4 * h;
                float4 bv = *(const float4*)&bias[o_base];
                const int q  = o_base >> 4;
                const int i0 = 4 * h;
                const int lp = (l & 31) + 32 * (j & 1);
                uint2 pk;
                pk.x = f2bf(acc[ct][4 * j + 0] + bv.x) | (f2bf(acc[ct][4 * j + 1] + bv.y) << 16);
                pk.y = f2bf(acc[ct][4 * j + 2] + bv.z) | (f2bf(acc[ct][4 * j + 3] + bv.w) << 16);
                size_t off = (((size_t)(b * 128 + ntile) * 4 + q) * 64 + lp) * 8 + i0;
                *(uint2*)&buf[off] = pk;
            }
        }
    } else {
        const int ntile = bx * 4 + w;
        #pragma unroll
        for (int ct = 0; ct < 4; ++ct) {
            const int ctile = (y - 1) * 4 + ct;
            const float hb = h_b[ctile * 32 + (l & 31)];
            #pragma unroll
            for (int j = 0; j < 4; ++j) {
                const int q  = ntile * 2 + (j >> 1);
                const int i0 = 4 * h;
                const int lp = (l & 31) + 32 * (j & 1);
                uint2 pk;
                pk.x = f2bf(acc[ct][4 * j + 0] + hb) | (f2bf(acc[ct][4 * j + 1] + hb) << 16);
                pk.y = f2bf(acc[ct][4 * j + 2] + hb) | (f2bf(acc[ct][4 * j + 3] + hb) << 16);
                size_t off = (((size_t)(b * 16 + ctile) * 256 + q) * 64 + lp) * 8 + i0;
                *(uint2*)&ha[off] = pk;
            }
        }
    }
}

// ---------------------------------------------------------------------------
// attn: grid 512 (b, ch, mi per-XCD swizzled), block 512 (8 waves), 2 blocks/CU.
// Block = 64 queries x 256 channels; S duplicated across the ch pair.
__global__ __launch_bounds__(512, 4) void attn_kernel(
    const unsigned short* __restrict__ fa,
    const unsigned short* __restrict__ gbuf,
    const unsigned short* __restrict__ ha,
    const float* __restrict__ x,
    const float* __restrict__ gamma_p,
    float* __restrict__ out)
{
    __shared__ unsigned short Ebuf[2][64 * 136];
    __shared__ float den_part[4][64];
    __shared__ float den_inv[64];

    const int t     = threadIdx.x;
    const int w     = t >> 6;
    const int l     = t & 63;
    const int lane  = l & 31;
    const int half  = l >> 5;
    const int nsub  = w & 3;
    const int mhalf = w >> 2;

    // blk%8 fixes (ch, b) per XCD -> per-XCD h slice = 2 MB, L2-resident
    const int blk = blockIdx.x;
    const int ch  = blk & 1;
    const int b   = (blk >> 1) & 3;
    const int mi  = blk >> 3;
    const int m0  = mi * 64;

    bf16x8 gfrag[2][4];
    {
        const unsigned short* gp = gbuf
            + (((size_t)(b * 128 + (m0 >> 5)) * 4) * 512) + (size_t)l * 8;
        #pragma unroll
        for (int mt = 0; mt < 2; ++mt)
            #pragma unroll
            for (int q = 0; q < 4; ++q)
                gfrag[mt][q] = *(const bf16x8*)(gp + ((size_t)mt * 4 + q) * 512);
    }

    f32x16 acc[2];   // [mt], this wave's single c-tile
    #pragma unroll
    for (int j = 0; j < 2; ++j)
        #pragma unroll
        for (int r = 0; r < 16; ++r) acc[j][r] = 0.f;

    float denp = 0.f;

    const unsigned short* fbase = fa + ((size_t)b * 128 * 4) * 512;
    const unsigned short* hbase = ha + (((size_t)(b * 16 + ch * 8 + w)) * 256) * 512;

    for (int nt = 0; nt < 32; ++nt) {
        // ---- S phase (duplicated across ch pair) ----
        f32x16 s;
        #pragma unroll
        for (int r = 0; r < 16; ++r) s[r] = 0.f;
        const unsigned short* fp = fbase + ((size_t)(nt * 4 + nsub) * 4) * 512 + (size_t)l * 8;
        #pragma unroll
        for (int q = 0; q < 4; ++q) {
            bf16x8 af = *(const bf16x8*)(fp + (size_t)q * 512);
            s = __builtin_amdgcn_mfma_f32_32x32x16_bf16(af, gfrag[mhalf][q], s, 0, 0, 0);
        }
        unsigned short* ew = &Ebuf[nt & 1][(mhalf * 32 + lane) * 136 + nsub * 32 + half * 4];
        #pragma unroll
        for (int r4 = 0; r4 < 4; ++r4) {
            float e0 = __expf(s[r4 * 4 + 0]);
            float e1 = __expf(s[r4 * 4 + 1]);
            float e2 = __expf(s[r4 * 4 + 2]);
            float e3 = __expf(s[r4 * 4 + 3]);
            denp += (e0 + e1) + (e2 + e3);
            uint2 pk;
            pk.x = f2bf(e0) | (f2bf(e1) << 16);
            pk.y = f2bf(e2) | (f2bf(e3) << 16);
            *(uint2*)(ew + r4 * 8) = pk;
        }
        __syncthreads();
        // ---- PV phase: this wave's 32-channel tile ----
        const unsigned short* hp = hbase + (size_t)(nt * 8) * 512 + (size_t)l * 8;
        const unsigned short* eb = &Ebuf[nt & 1][0];
        #pragma unroll
        for (int q = 0; q < 8; ++q) {
            bf16x8 a0 = *(const bf16x8*)(hp + (size_t)q * 512);
            bf16x8 b0 = *(const bf16x8*)(eb + (lane)      * 136 + q * 16 + half * 8);
            bf16x8 b1 = *(const bf16x8*)(eb + (32 + lane) * 136 + q * 16 + half * 8);
            acc[0] = __builtin_amdgcn_mfma_f32_32x32x16_bf16(a0, b0, acc[0], 0, 0, 0);
            acc[1] = __builtin_amdgcn_mfma_f32_32x32x16_bf16(a0, b1, acc[1], 0, 0, 0);
        }
    }

    denp += __shfl_xor(denp, 32, 64);
    if (l < 32) den_part[nsub][mhalf * 32 + lane] = denp;
    __syncthreads();
    if (t < 64) {
        float d = den_part[0][t] + den_part[1][t] + den_part[2][t] + den_part[3][t];
        den_inv[t] = 1.0f / d;
    }
    __syncthreads();

    const float gs = gamma_p[0];
    #pragma unroll
    for (int mt = 0; mt < 2; ++mt) {
        const float dinv = den_inv[mt * 32 + lane];
        const int m = m0 + mt * 32 + lane;
        #pragma unroll
        for (int r = 0; r < 16; ++r) {
            const int c = (ch * 8 + w) * 32 + (r & 3) + ((r >> 2) * 8) + half * 4;
            const size_t idx = ((size_t)(b * C_IN + c)) * N_PIX + m;
            out[idx] = gs * acc[mt][r] * dinv + x[idx];
        }
    }
}

// ---------------------------------------------------------------------------
extern "C" void kernel_launch(void* const* d_in, const int* in_sizes, int n_in,
                              void* d_out, int out_size, void* d_ws, size_t ws_size,
                              hipStream_t stream)
{
    const float* x     = (const float*)d_in[0];
    const float* f_w   = (const float*)d_in[1];
    const float* f_b   = (const float*)d_in[2];
    const float* g_w   = (const float*)d_in[3];
    const float* g_b   = (const float*)d_in[4];
    const float* h_w   = (const float*)d_in[5];
    const float* h_b   = (const float*)d_in[6];
    const float* gamma = (const float*)d_in[7];
    float* out = (float*)d_out;

    unsigned short* fa   = (unsigned short*)d_ws;        // 1M shorts (2 MB)
    unsigned short* gbuf = fa + (1u << 20);              // 1M shorts
    unsigned short* ha   = gbuf + (1u << 20);            // 8M shorts (16 MB)
    unsigned short* xb   = ha + (8u << 20);              // 8M shorts (16 MB)
    unsigned short* wfg  = xb + (8u << 20);              // 64K shorts
    unsigned short* whb  = wfg + (1u << 16);             // 256K shorts

    pack_w<<<160, 256, 0, stream>>>(f_w, g_w, h_w, wfg, whb);

    dim3 gx(64, 4, 4);
    pack_x<<<gx, 256, 0, stream>>>(x, xb);

    dim3 gp(32, 5, 4);
    proj_gemm<<<gp, 256, 0, stream>>>(xb, wfg, whb, f_b, g_b, h_b, fa, gbuf, ha);

    attn_kernel<<<512, 512, 0, stream>>>(fa, gbuf, ha, x, gamma, out);
}

// Round 5
// 219.580 us; speedup vs baseline: 9.0020x; 1.1346x over previous
//
#include <hip/hip_runtime.h>

// Self-attention (SAGAN-style), B=4, C=512, N=4096, O=64.
// Round 5:
//   attn: 256 blocks x 512 thr (1 block/CU, 8 waves). Block = 128 m x 256 c.
//         Wave = 64c x 64m PV tile (acc 64 VGPR), 2 S-tiles/wave sharing one
//         f fragment. All 16 h fragments register-prefetched before the
//         barrier to hide L2 latency. v_cvt_pk_bf16_f32 for E packing.
//   proj_gemm: double-buffered LDS staging (stage k+1 issued before MFMA(k),
//         single barrier per iter).
//   pack_w / pack_x: unchanged.
// Fragment chunk convention (32-row tiles):
//   chunk[tile][q][lane][i] = M[idx = tile*32 + (lane&31)][k = q*16 + (lane>>5)*8 + i]

#define N_PIX 4096
#define C_IN  512

typedef __attribute__((ext_vector_type(8)))  short bf16x8;
typedef __attribute__((ext_vector_type(16))) float f32x16;

typedef __attribute__((address_space(1))) const unsigned int guint;
typedef __attribute__((address_space(3))) unsigned int luint;

__device__ __forceinline__ void gload_lds16(const void* g, void* l) {
    __builtin_amdgcn_global_load_lds((guint*)g, (luint*)l, 16, 0, 0);
}

__device__ inline unsigned int f2bf(float f) {
    union { float f; unsigned u; } x; x.f = f;
    unsigned r = x.u + 0x7FFFu + ((x.u >> 16) & 1u);
    return r >> 16;
}

__device__ __forceinline__ unsigned cvt_pk_bf16(float a, float b) {
#if __has_builtin(__builtin_amdgcn_cvt_pk_bf16_f32)
    auto r = __builtin_amdgcn_cvt_pk_bf16_f32(a, b);
    unsigned u; __builtin_memcpy(&u, &r, 4); return u;
#else
    return f2bf(a) | (f2bf(b) << 16);
#endif
}

// ---------------------------------------------------------------------------
// pack_w: 40960 octets. [0,8192): wfg (f/g A-frag); [8192,40960): whb (h B-frag).
__global__ __launch_bounds__(256) void pack_w(
    const float* __restrict__ f_w, const float* __restrict__ g_w,
    const float* __restrict__ h_w,
    unsigned short* __restrict__ wfg, unsigned short* __restrict__ whb)
{
    const int idx = blockIdx.x * 256 + threadIdx.x;
    const float* W;
    unsigned short* dst;
    int sub;
    if (idx < 8192) {
        const int ot = idx >> 11, rem = idx & 2047;
        const int q = rem >> 6, l = rem & 63;
        const int o = ot * 32 + (l & 31);
        W = (o < 64) ? &f_w[(size_t)o * C_IN] : &g_w[(size_t)(o - 64) * C_IN];
        dst = wfg; sub = idx;
        W += q * 16 + (l >> 5) * 8;
    } else {
        const int id2 = idx - 8192;
        const int ct = id2 >> 11, rem = id2 & 2047;
        const int q = rem >> 6, l = rem & 63;
        const int co = ct * 32 + (l & 31);
        W = &h_w[(size_t)co * C_IN + q * 16 + (l >> 5) * 8];
        dst = whb; sub = id2;
    }
    float4 v0 = *(const float4*)(W);
    float4 v1 = *(const float4*)(W + 4);
    uint4 pk;
    pk.x = cvt_pk_bf16(v0.x, v0.y);
    pk.y = cvt_pk_bf16(v0.z, v0.w);
    pk.z = cvt_pk_bf16(v1.x, v1.y);
    pk.w = cvt_pk_bf16(v1.z, v1.w);
    *(uint4*)&dst[(size_t)sub * 8] = pk;
}

// ---------------------------------------------------------------------------
// pack_x: x[b,c,n] fp32 -> frag chunks. grid (64, 4, B), block 256.
__global__ __launch_bounds__(256) void pack_x(
    const float* __restrict__ x, unsigned short* __restrict__ xb)
{
    __shared__ unsigned short Ls[128 * 66];
    const int t  = threadIdx.x;
    const int n0 = blockIdx.x * 64;
    const int c0 = blockIdx.y * 128;
    const int b  = blockIdx.z;

    {
        const int c = t >> 1, half = t & 1;
        const float* xp = &x[((size_t)(b * C_IN + c0 + c)) * N_PIX + n0 + half * 32];
        #pragma unroll
        for (int k = 0; k < 8; ++k) {
            float4 v = *(const float4*)&xp[k * 4];
            uint2 pk;
            pk.x = cvt_pk_bf16(v.x, v.y);
            pk.y = cvt_pk_bf16(v.z, v.w);
            *(uint2*)&Ls[c * 66 + half * 32 + k * 4] = pk;
        }
    }
    __syncthreads();
    const int n = t & 63;
    #pragma unroll
    for (int p = 0; p < 4; ++p) {
        const int j = (t >> 6) + p * 4;
        unsigned short tmp[8];
        #pragma unroll
        for (int k = 0; k < 8; ++k) tmp[k] = Ls[(j * 8 + k) * 66 + n];
        uint4 pk;
        pk.x = tmp[0] | ((unsigned)tmp[1] << 16);
        pk.y = tmp[2] | ((unsigned)tmp[3] << 16);
        pk.z = tmp[4] | ((unsigned)tmp[5] << 16);
        pk.w = tmp[6] | ((unsigned)tmp[7] << 16);
        const int cbase = c0 + j * 8;
        const int q  = cbase >> 4;
        const int hf = (cbase >> 3) & 1;
        const int ng = n0 + n;
        size_t off = (((size_t)(b * 128 + (ng >> 5)) * 32 + q) * 64
                      + ((ng & 31) + 32 * hf)) * 8;
        *(uint4*)&xb[off] = pk;
    }
}

// ---------------------------------------------------------------------------
// proj_gemm: grid (32, 5, B), block 256 (4 waves). 128x128 tile, K=512,
// double-buffered LDS staging (BK=64) via global_load_lds.
__global__ __launch_bounds__(256) void proj_gemm(
    const unsigned short* __restrict__ xb,
    const unsigned short* __restrict__ wfg,
    const unsigned short* __restrict__ whb,
    const float* __restrict__ f_b, const float* __restrict__ g_b,
    const float* __restrict__ h_b,
    unsigned short* __restrict__ fa, unsigned short* __restrict__ gbuf,
    unsigned short* __restrict__ ha)
{
    __shared__ __align__(16) unsigned short Ls[2][32 * 512];   // 64 KB
    const int t = threadIdx.x;
    const int w = t >> 6;
    const int l = t & 63;
    const int bx = blockIdx.x, y = blockIdx.y, b = blockIdx.z;

    const unsigned short* abase;
    const unsigned short* bbase;
    if (y == 0) {
        abase = wfg;
        bbase = xb + (size_t)((b * 128 + bx * 4) * 32) * 512;
    } else {
        abase = xb + (size_t)((b * 128 + bx * 4) * 32) * 512;
        bbase = whb + (size_t)(((y - 1) * 4) * 32) * 512;
    }

    f32x16 acc[4];
    #pragma unroll
    for (int ct = 0; ct < 4; ++ct)
        #pragma unroll
        for (int r = 0; r < 16; ++r) acc[ct][r] = 0.f;

    // stage it=0
    #pragma unroll
    for (int j = 0; j < 8; ++j) {
        const int chunk = w * 8 + j;
        const unsigned short* src;
        if (chunk < 16)
            src = abase + (size_t)((chunk >> 2) * 32 + (chunk & 3)) * 512;
        else {
            const int c2 = chunk - 16;
            src = bbase + (size_t)((c2 >> 2) * 32 + (c2 & 3)) * 512;
        }
        gload_lds16(src + (size_t)l * 8, &Ls[0][chunk * 512]);
    }
    __syncthreads();

    for (int it = 0; it < 8; ++it) {
        if (it < 7) {
            #pragma unroll
            for (int j = 0; j < 8; ++j) {
                const int chunk = w * 8 + j;
                const unsigned short* src;
                if (chunk < 16)
                    src = abase + (size_t)((chunk >> 2) * 32 + (it + 1) * 4 + (chunk & 3)) * 512;
                else {
                    const int c2 = chunk - 16;
                    src = bbase + (size_t)((c2 >> 2) * 32 + (it + 1) * 4 + (c2 & 3)) * 512;
                }
                gload_lds16(src + (size_t)l * 8, &Ls[(it + 1) & 1][chunk * 512]);
            }
        }
        const unsigned short* cur = &Ls[it & 1][0];
        #pragma unroll
        for (int qq = 0; qq < 4; ++qq) {
            bf16x8 av = *(const bf16x8*)&cur[(w * 4 + qq) * 512 + l * 8];
            #pragma unroll
            for (int ct = 0; ct < 4; ++ct) {
                bf16x8 bv = *(const bf16x8*)&cur[(16 + ct * 4 + qq) * 512 + l * 8];
                acc[ct] = __builtin_amdgcn_mfma_f32_32x32x16_bf16(av, bv, acc[ct], 0, 0, 0);
            }
        }
        __syncthreads();
    }

    const int h = l >> 5;
    if (y == 0) {
        unsigned short* buf = (w < 2) ? fa : gbuf;
        const float* bias = (w < 2) ? f_b : g_b;
        #pragma unroll
        for (int ct = 0; ct < 4; ++ct) {
            const int ntile = bx * 4 + ct;
            #pragma unroll
            for (int j = 0; j < 4; ++j) {
                const int o_base = (w & 1) * 32 + 8 * j + 4 * h;
                float4 bv = *(const float4*)&bias[o_base];
                const int q  = o_base >> 4;
                const int i0 = 4 * h;
                const int lp = (l & 31) + 32 * (j & 1);
                uint2 pk;
                pk.x = cvt_pk_bf16(acc[ct][4 * j + 0] + bv.x, acc[ct][4 * j + 1] + bv.y);
                pk.y = cvt_pk_bf16(acc[ct][4 * j + 2] + bv.z, acc[ct][4 * j + 3] + bv.w);
                size_t off = (((size_t)(b * 128 + ntile) * 4 + q) * 64 + lp) * 8 + i0;
                *(uint2*)&buf[off] = pk;
            }
        }
    } else {
        const int ntile = bx * 4 + w;
        #pragma unroll
        for (int ct = 0; ct < 4; ++ct) {
            const int ctile = (y - 1) * 4 + ct;
            const float hb = h_b[ctile * 32 + (l & 31)];
            #pragma unroll
            for (int j = 0; j < 4; ++j) {
                const int q  = ntile * 2 + (j >> 1);
                const int i0 = 4 * h;
                const int lp = (l & 31) + 32 * (j & 1);
                uint2 pk;
                pk.x = cvt_pk_bf16(acc[ct][4 * j + 0] + hb, acc[ct][4 * j + 1] + hb);
                pk.y = cvt_pk_bf16(acc[ct][4 * j + 2] + hb, acc[ct][4 * j + 3] + hb);
                size_t off = (((size_t)(b * 16 + ctile) * 256 + q) * 64 + lp) * 8 + i0;
                *(uint2*)&ha[off] = pk;
            }
        }
    }
}

// ---------------------------------------------------------------------------
// attn: grid 256 (1 block/CU), block 512 (8 waves).
// Block = 128 m x 256 c. Wave = 64c x 64m. n-chunk = 128 per iter, 32 iters.
// Wave w: cw=w&3 (c-quarter, also S n-subtile), mw=w>>2 (m-half).
__global__ __launch_bounds__(512, 2) void attn_kernel(
    const unsigned short* __restrict__ fa,
    const unsigned short* __restrict__ gbuf,
    const unsigned short* __restrict__ ha,
    const float* __restrict__ x,
    const float* __restrict__ gamma_p,
    float* __restrict__ out)
{
    __shared__ unsigned short Ebuf[2][128 * 136];  // E[m_local][n], 272B rows
    __shared__ float den_part[4][128];
    __shared__ float den_inv[128];

    const int t    = threadIdx.x;
    const int w    = t >> 6;
    const int l    = t & 63;
    const int lane = l & 31;
    const int half = l >> 5;
    const int cw   = w & 3;    // c-quarter within 256-c slice; also S n-subtile
    const int mw   = w >> 1 >> 1; // m-half (w>>2)

    // blk%8 fixes (chalf, b) per XCD -> per-XCD h slice 2 MB, L2-resident
    const int blk   = blockIdx.x;
    const int chalf = blk & 1;
    const int b     = (blk >> 1) & 3;
    const int mi    = blk >> 3;       // 0..31
    const int m0    = mi * 128;

    // persistent g fragments for this wave's two 32-m tiles
    bf16x8 gfrag[2][4];
    {
        const int mtg = mi * 4 + mw * 2;   // global 32-m tile index base
        const unsigned short* gp = gbuf
            + (((size_t)(b * 128 + mtg)) * 4) * 512 + (size_t)l * 8;
        #pragma unroll
        for (int j = 0; j < 2; ++j)
            #pragma unroll
            for (int q = 0; q < 4; ++q)
                gfrag[j][q] = *(const bf16x8*)(gp + ((size_t)j * 4 + q) * 512);
    }

    f32x16 acc[2][2];   // [ct][mt]
    #pragma unroll
    for (int i = 0; i < 2; ++i)
        #pragma unroll
        for (int j = 0; j < 2; ++j)
            #pragma unroll
            for (int r = 0; r < 16; ++r) acc[i][j][r] = 0.f;

    float denp[2] = {0.f, 0.f};

    const int ctg0 = chalf * 8 + cw * 2;   // global 32-c tile of acc[0]
    const unsigned short* fbase = fa + ((size_t)b * 128 * 4) * 512 + (size_t)l * 8;
    const unsigned short* hbase = ha + (((size_t)(b * 16 + ctg0)) * 256) * 512 + (size_t)l * 8;

    for (int nt = 0; nt < 32; ++nt) {
        // ---- issue f loads (needed first) then h prefetch (needed post-barrier)
        bf16x8 ff[4];
        {
            const unsigned short* fp = fbase + ((size_t)(nt * 4 + cw) * 4) * 512;
            #pragma unroll
            for (int q = 0; q < 4; ++q)
                ff[q] = *(const bf16x8*)(fp + (size_t)q * 512);
        }
        bf16x8 hreg[2][8];
        {
            const unsigned short* hp = hbase + (size_t)(nt * 8) * 512;
            #pragma unroll
            for (int q = 0; q < 8; ++q) {
                hreg[0][q] = *(const bf16x8*)(hp + (size_t)q * 512);
                hreg[1][q] = *(const bf16x8*)(hp + (size_t)(256 * 512) + (size_t)q * 512);
            }
        }
        // ---- S phase: two 32x32 tiles (m-tiles mw*2, mw*2+1), same f ----
        #pragma unroll
        for (int j = 0; j < 2; ++j) {
            f32x16 s;
            #pragma unroll
            for (int r = 0; r < 16; ++r) s[r] = 0.f;
            #pragma unroll
            for (int q = 0; q < 4; ++q)
                s = __builtin_amdgcn_mfma_f32_32x32x16_bf16(ff[q], gfrag[j][q], s, 0, 0, 0);
            unsigned short* ew = &Ebuf[nt & 1][((mw * 2 + j) * 32 + lane) * 136
                                              + cw * 32 + half * 4];
            float dp = 0.f;
            #pragma unroll
            for (int r4 = 0; r4 < 4; ++r4) {
                float e0 = __expf(s[r4 * 4 + 0]);
                float e1 = __expf(s[r4 * 4 + 1]);
                float e2 = __expf(s[r4 * 4 + 2]);
                float e3 = __expf(s[r4 * 4 + 3]);
                dp += (e0 + e1) + (e2 + e3);
                uint2 pk;
                pk.x = cvt_pk_bf16(e0, e1);
                pk.y = cvt_pk_bf16(e2, e3);
                *(uint2*)(ew + r4 * 8) = pk;
            }
            denp[j] += dp;
        }
        __syncthreads();
        // ---- PV phase: 64c x 64m, h already in registers ----
        const unsigned short* eb = &Ebuf[nt & 1][0];
        const int mrow0 = (mw * 2) * 32 + lane;
        #pragma unroll
        for (int q = 0; q < 8; ++q) {
            bf16x8 b0 = *(const bf16x8*)(eb + mrow0 * 136 + q * 16 + half * 8);
            bf16x8 b1 = *(const bf16x8*)(eb + (mrow0 + 32) * 136 + q * 16 + half * 8);
            acc[0][0] = __builtin_amdgcn_mfma_f32_32x32x16_bf16(hreg[0][q], b0, acc[0][0], 0, 0, 0);
            acc[0][1] = __builtin_amdgcn_mfma_f32_32x32x16_bf16(hreg[0][q], b1, acc[0][1], 0, 0, 0);
            acc[1][0] = __builtin_amdgcn_mfma_f32_32x32x16_bf16(hreg[1][q], b0, acc[1][0], 0, 0, 0);
            acc[1][1] = __builtin_amdgcn_mfma_f32_32x32x16_bf16(hreg[1][q], b1, acc[1][1], 0, 0, 0);
        }
        // single barrier per iter: E double-buffered (write of iter k+2's buffer
        // is gated by barrier k+1, which post-dates every wave's PV(k) read).
    }

    // ---- denominator reduction over the 4 n-subtile waves ----
    #pragma unroll
    for (int j = 0; j < 2; ++j) {
        denp[j] += __shfl_xor(denp[j], 32, 64);
        if (l < 32) den_part[cw][(mw * 2 + j) * 32 + lane] = denp[j];
    }
    __syncthreads();
    if (t < 128) {
        float d = den_part[0][t] + den_part[1][t] + den_part[2][t] + den_part[3][t];
        den_inv[t] = 1.0f / d;
    }
    __syncthreads();

    // ---- epilogue: out = gamma * O/den + x ----
    const float gs = gamma_p[0];
    #pragma unroll
    for (int ct = 0; ct < 2; ++ct) {
        #pragma unroll
        for (int mt = 0; mt < 2; ++mt) {
            const int mloc = (mw * 2 + mt) * 32 + lane;
            const float dinv = den_inv[mloc];
            const int m = m0 + mloc;
            #pragma unroll
            for (int r = 0; r < 16; ++r) {
                const int c = (ctg0 + ct) * 32 + (r & 3) + ((r >> 2) * 8) + half * 4;
                const size_t idx = ((size_t)(b * C_IN + c)) * N_PIX + m;
                out[idx] = gs * acc[ct][mt][r] * dinv + x[idx];
            }
        }
    }
}

// ---------------------------------------------------------------------------
extern "C" void kernel_launch(void* const* d_in, const int* in_sizes, int n_in,
                              void* d_out, int out_size, void* d_ws, size_t ws_size,
                              hipStream_t stream)
{
    const float* x     = (const float*)d_in[0];
    const float* f_w   = (const float*)d_in[1];
    const float* f_b   = (const float*)d_in[2];
    const float* g_w   = (const float*)d_in[3];
    const float* g_b   = (const float*)d_in[4];
    const float* h_w   = (const float*)d_in[5];
    const float* h_b   = (const float*)d_in[6];
    const float* gamma = (const float*)d_in[7];
    float* out = (float*)d_out;

    unsigned short* fa   = (unsigned short*)d_ws;        // 1M shorts (2 MB)
    unsigned short* gbuf = fa + (1u << 20);              // 1M shorts
    unsigned short* ha   = gbuf + (1u << 20);            // 8M shorts (16 MB)
    unsigned short* xb   = ha + (8u << 20);              // 8M shorts (16 MB)
    unsigned short* wfg  = xb + (8u << 20);              // 64K shorts
    unsigned short* whb  = wfg + (1u << 16);             // 256K shorts

    pack_w<<<160, 256, 0, stream>>>(f_w, g_w, h_w, wfg, whb);

    dim3 gx(64, 4, 4);
    pack_x<<<gx, 256, 0, stream>>>(x, xb);

    dim3 gp(32, 5, 4);
    proj_gemm<<<gp, 256, 0, stream>>>(xb, wfg, whb, f_b, g_b, h_b, fa, gbuf, ha);

    attn_kernel<<<256, 512, 0, stream>>>(fa, gbuf, ha, x, gamma, out);
}